// Round 10
// baseline (962.116 us; speedup 1.0000x reference)
//
#include <hip/hip_runtime.h>
#include <math.h>

#define BB 2
#define CC 512
#define HH 30
#define WW 40
#define KK 64
#define NPIX (HH*WW)
#define HP 27
#define WP 37
#define NP (HP*WP)
#define LEPS 1e-12f

// ---------------------------------------------------------------------------
// Kernel 1: per-(b,h) row: channel L2-norm, xn store, logits (K=64) + softmax.
// ---------------------------------------------------------------------------
__global__ __launch_bounds__(512) void k_norm_soft(
    const float* __restrict__ x, const float* __restrict__ convw,
    float* __restrict__ xn, float* __restrict__ soft)
{
  const int h = blockIdx.x, b = blockIdx.y;
  const int t = threadIdx.x;
  __shared__ float xc[64][41];
  __shared__ float cw[64][65];
  __shared__ float Lb[KK][WW + 1];
  __shared__ float psum[12][WW];
  __shared__ float invn[WW];
  __shared__ float mx[WW], Zs[WW];

  const size_t xbase = (size_t)b * CC * NPIX + (size_t)h * WW;

  if (t < 480) {
    const int w = t % 40, part = t / 40;
    float s = 0.f;
    for (int c = part; c < CC; c += 12) {
      const float v = x[xbase + (size_t)c * NPIX + w];
      s = fmaf(v, v, s);
    }
    psum[part][w] = s;
  }
  __syncthreads();
  if (t < 40) {
    float s = 0.f;
    #pragma unroll
    for (int p = 0; p < 12; ++p) s += psum[p][t];
    invn[t] = 1.f / fmaxf(sqrtf(s), LEPS);
  }
  __syncthreads();

  const int k = t & 63, wp = t >> 6;
  float acc[5] = {0.f, 0.f, 0.f, 0.f, 0.f};
  for (int cb = 0; cb < CC; cb += 64) {
    #pragma unroll
    for (int n = 0; n < 5; ++n) {
      const int idx = t + 512 * n;
      const int c = idx / 40, w = idx % 40;
      const float v = x[xbase + (size_t)(cb + c) * NPIX + w] * invn[w];
      xc[c][w] = v;
      xn[xbase + (size_t)(cb + c) * NPIX + w] = v;
    }
    #pragma unroll
    for (int n = 0; n < 8; ++n) {
      const int idx = t + 512 * n;
      const int kk2 = idx >> 6, c2 = idx & 63;
      cw[kk2][c2] = convw[(size_t)kk2 * CC + cb + c2];
    }
    __syncthreads();
    #pragma unroll 1
    for (int c = 0; c < 64; ++c) {
      const float cv = cw[k][c];
      #pragma unroll
      for (int n = 0; n < 5; ++n)
        acc[n] = fmaf(cv, xc[c][wp + 8 * n], acc[n]);
    }
    __syncthreads();
  }
  #pragma unroll
  for (int n = 0; n < 5; ++n) Lb[k][wp + 8 * n] = acc[n];
  __syncthreads();
  if (t < 40) {
    float m = -1e30f;
    for (int kk2 = 0; kk2 < KK; ++kk2) m = fmaxf(m, Lb[kk2][t]);
    float Z = 0.f;
    for (int kk2 = 0; kk2 < KK; ++kk2) Z += expf(Lb[kk2][t] - m);
    mx[t] = m; Zs[t] = Z;
  }
  __syncthreads();
  const size_t sbase = (size_t)b * KK * NPIX + (size_t)h * WW;
  #pragma unroll
  for (int n = 0; n < 5; ++n) {
    const int idx = t + 512 * n;
    const int kk2 = idx / 40, w = idx % 40;
    soft[sbase + (size_t)kk2 * NPIX + w] = expf(Lb[kk2][w] - mx[w]) / Zs[w];
  }
}

// ---------------------------------------------------------------------------
// Kernel G: per-(b,k) global VLAD row, first L2 norm over c.
// ---------------------------------------------------------------------------
__global__ __launch_bounds__(256) void k_global(
    const float* __restrict__ xn, const float* __restrict__ soft,
    const float* __restrict__ cent, float* __restrict__ ghat)
{
  const int k = blockIdx.x, b = blockIdx.y, t = threadIdx.x;
  __shared__ float sb[NPIX];
  __shared__ float red[256];
  const float* srow = soft + ((size_t)b * KK + k) * NPIX;
  for (int i2 = t; i2 < NPIX; i2 += 256) sb[i2] = srow[i2];
  __syncthreads();
  float p = 0.f;
  for (int i2 = t; i2 < NPIX; i2 += 256) p += sb[i2];
  red[t] = p;
  __syncthreads();
  for (int s = 128; s > 0; s >>= 1) { if (t < s) red[t] += red[t + s]; __syncthreads(); }
  const float Sg = red[0];
  __syncthreads();

  const int c0 = t, c1 = t + 256;
  const float* x0 = xn + ((size_t)b * CC + c0) * NPIX;
  const float* x1 = xn + ((size_t)b * CC + c1) * NPIX;
  float a0 = 0.f, a1 = 0.f;
  for (int p4 = 0; p4 < NPIX; p4 += 4) {
    const float4 s4 = *(const float4*)&sb[p4];
    const float4 v0 = *(const float4*)(x0 + p4);
    const float4 v1 = *(const float4*)(x1 + p4);
    a0 = fmaf(s4.x, v0.x, a0); a0 = fmaf(s4.y, v0.y, a0);
    a0 = fmaf(s4.z, v0.z, a0); a0 = fmaf(s4.w, v0.w, a0);
    a1 = fmaf(s4.x, v1.x, a1); a1 = fmaf(s4.y, v1.y, a1);
    a1 = fmaf(s4.z, v1.z, a1); a1 = fmaf(s4.w, v1.w, a1);
  }
  const float g0 = a0 - cent[(size_t)k * CC + c0] * Sg;
  const float g1 = a1 - cent[(size_t)k * CC + c1] * Sg;
  red[t] = g0 * g0 + g1 * g1;
  __syncthreads();
  for (int s = 128; s > 0; s >>= 1) { if (t < s) red[t] += red[t + s]; __syncthreads(); }
  const float inv = 1.f / fmaxf(sqrtf(red[0]), LEPS);
  float* gr = ghat + ((size_t)b * KK + k) * CC;
  gr[c0] = g0 * inv; gr[c1] = g1 * inv;
}

// Global second norm: (a) per-b sum of squares -> inv scale, (b) wide scale.
__global__ __launch_bounds__(256) void k_g2a(
    const float* __restrict__ ghat, float* __restrict__ inv2g)
{
  const int b = blockIdx.x, t = threadIdx.x;
  __shared__ float red[256];
  const float* gb = ghat + (size_t)b * KK * CC;
  float p = 0.f;
  for (int i2 = t; i2 < KK * CC; i2 += 256) { const float v = gb[i2]; p = fmaf(v, v, p); }
  red[t] = p;
  __syncthreads();
  for (int s = 128; s > 0; s >>= 1) { if (t < s) red[t] += red[t + s]; __syncthreads(); }
  if (t == 0) inv2g[b] = 1.f / fmaxf(sqrtf(red[0]), LEPS);
}

__global__ __launch_bounds__(256) void k_g2b(
    const float* __restrict__ ghat, const float* __restrict__ inv2g,
    float* __restrict__ outg)
{
  const int b = blockIdx.y;
  const int u = blockIdx.x * 256 + threadIdx.x;
  if (u < KK * CC)
    outg[(size_t)b * KK * CC + u] = ghat[(size_t)b * KK * CC + u] * inv2g[b];
}

// ---------------------------------------------------------------------------
// Kernel RAW: compute raw = 16*box ONCE, store canonical [bk][c][i][j].
// Built from v7's proven parts: 7-row slab staged once, barrier-free row
// loop, j = t%40 lane map (consecutive-lane stores, WRITE ~1.16x ideal).
// Widened to 8k x 4c per thread (48 LDS reads : 128 FMA per row,
// dx-innermost keeps ~75 live regs). Grid kg-fastest: the 8 blocks sharing
// an xn slab are consecutive -> L2 hits on the slab fetch.
// ---------------------------------------------------------------------------
__global__ __launch_bounds__(320, 4) void k_raw(
    const float* __restrict__ xn, const float* __restrict__ soft,
    const float* __restrict__ cent, float* __restrict__ outr)
{
  const int kg = blockIdx.x;             // 0..7  (8 k)   fastest -> slab reuse
  const int cg = blockIdx.y;             // 0..15 (32 c)
  const int bz = blockIdx.z;             // b*7 + iq
  const int b = bz / 7, iq = bz % 7;
  const int i0 = iq * 4;
  const int n_i = (iq == 6) ? 3 : 4;
  const int k0 = kg * 8, c0 = cg * 32;
  const int t = threadIdx.x;
  const int j = t % 40, c8 = t / 40;     // lanes consecutive in j

  __shared__ float xn_l[32][280];        // [c][rl*40+w]  35840 B
  __shared__ float soft_l[8][280];       //                8960 B
  __shared__ float cent_l[8][32];        //                1024 B -> 45.8 KB

  // stage xn slab: 32 c x 7 rows x 40 w (rows clamped at image edge)
  for (int u = t; u < 2240; u += 320) {
    const int c = u / 70, rem = u - c * 70;
    const int rl = rem / 10, q = rem - rl * 10;
    int row = i0 + rl; if (row > HH - 1) row = HH - 1;
    *(float4*)&xn_l[c][rl * 40 + q * 4] =
      *(const float4*)&xn[((size_t)(b * CC + c0 + c)) * NPIX + (size_t)row * 40 + q * 4];
  }
  for (int u = t; u < 560; u += 320) {
    const int kk = u / 70, rem = u - kk * 70;
    const int rl = rem / 10, q = rem - rl * 10;
    int row = i0 + rl; if (row > HH - 1) row = HH - 1;
    *(float4*)&soft_l[kk][rl * 40 + q * 4] =
      *(const float4*)&soft[((size_t)(b * KK + k0 + kk)) * NPIX + (size_t)row * 40 + q * 4];
  }
  if (t < 256) cent_l[t >> 5][t & 31] = cent[(size_t)(k0 + (t >> 5)) * CC + c0 + (t & 31)];
  __syncthreads();

  for (int ii = 0; ii < n_i; ++ii) {
    const int i = i0 + ii;
    float acc[4][8];                     // [cc][kk]
    float Ssum[8];
    #pragma unroll
    for (int kk = 0; kk < 8; ++kk) Ssum[kk] = 0.f;
    #pragma unroll
    for (int cc = 0; cc < 4; ++cc)
      #pragma unroll
      for (int kk = 0; kk < 8; ++kk) acc[cc][kk] = 0.f;

    #pragma unroll
    for (int r = 0; r < 4; ++r) {
      const int base = (ii + r) * 40 + j;
      #pragma unroll
      for (int dx = 0; dx < 4; ++dx) {
        float sv[8], xv[4];
        #pragma unroll
        for (int kk = 0; kk < 8; ++kk) sv[kk] = soft_l[kk][base + dx];
        #pragma unroll
        for (int cc = 0; cc < 4; ++cc) xv[cc] = xn_l[cc * 8 + c8][base + dx];
        #pragma unroll
        for (int kk = 0; kk < 8; ++kk) Ssum[kk] += sv[kk];
        #pragma unroll
        for (int cc = 0; cc < 4; ++cc)
          #pragma unroll
          for (int kk = 0; kk < 8; ++kk)
            acc[cc][kk] = fmaf(xv[cc], sv[kk], acc[cc][kk]);
      }
    }

    if (j < WP) {
      #pragma unroll
      for (int kk = 0; kk < 8; ++kk) {
        const size_t bk = (size_t)(b * KK + k0 + kk);
        #pragma unroll
        for (int cc = 0; cc < 4; ++cc) {
          const float raw = fmaf(-cent_l[kk][cc * 8 + c8], Ssum[kk], acc[cc][kk]);
          outr[(bk * CC + c0 + cc * 8 + c8) * NP + (size_t)i * WP + j] = raw;
        }
      }
    }
  }
}

// ---------------------------------------------------------------------------
// Kernel SSQ: ssq[bk][p] = sum_c raw^2 — coalesced stream over raw (proven R8).
// ---------------------------------------------------------------------------
__global__ __launch_bounds__(256) void k_ssq(
    const float* __restrict__ outr, float* __restrict__ ssq)
{
  const int pb = blockIdx.x;             // 8 strips of 128 p
  const int bk = blockIdx.y;             // 128
  const int t = threadIdx.x;
  const int pl = t & 127, ch = t >> 7;
  const int p = pb * 128 + pl;
  __shared__ float red[2][128];
  float s = 0.f;
  if (p < NP) {
    const float* base = outr + ((size_t)bk * CC + ch * 256) * NP + p;
    #pragma unroll 8
    for (int c = 0; c < 256; ++c) {
      const float v = base[(size_t)c * NP];
      s = fmaf(v, v, s);
    }
  }
  red[ch][pl] = s;
  __syncthreads();
  if (t < 128 && p < NP)
    ssq[(size_t)bk * NP + p] = red[0][pl] + red[1][pl];
}

// ---------------------------------------------------------------------------
// Kernel NF_b: per (b,i): exact per-(b,k,p) scale incl. cross-k second norm.
// ---------------------------------------------------------------------------
__global__ __launch_bounds__(256) void k_nf_b(
    const float* __restrict__ ssq, float* __restrict__ fs)
{
  const int i = blockIdx.x, b = blockIdx.y, t = threadIdx.x;
  __shared__ float sL[64][37];
  __shared__ float inv2[37];
  for (int u = t; u < 64 * 37; u += 256) {
    const int k = u / 37, j = u - (u / 37) * 37;
    sL[k][j] = ssq[((size_t)(b * KK + k)) * NP + (size_t)i * WP + j];
  }
  __syncthreads();
  if (t < 37) {
    float n2s = 0.f;
    for (int k = 0; k < 64; ++k) {
      const float sr = sL[k][t];
      const float iv = 1.f / fmaxf(sqrtf(sr) * 0.0625f, LEPS);
      n2s += sr * (1.f / 256.f) * iv * iv;
    }
    inv2[t] = 1.f / fmaxf(sqrtf(n2s), LEPS);
  }
  __syncthreads();
  for (int u = t; u < 64 * 37; u += 256) {
    const int k = u / 37, j = u - (u / 37) * 37;
    const float sr = sL[k][j];
    const float iv = 1.f / fmaxf(sqrtf(sr) * 0.0625f, LEPS);
    fs[((size_t)(b * KK + k)) * NP + (size_t)i * WP + j] = 0.0625f * iv * inv2[j];
  }
}

// ---------------------------------------------------------------------------
// Kernel SCALE: in-place out[u] *= fs[bk][p]; aligned float4 RMW (proven R8).
// ---------------------------------------------------------------------------
__global__ __launch_bounds__(256) void k_scale(
    float* __restrict__ outr, const float* __restrict__ fs)
{
  const size_t NV = (size_t)BB * KK * CC * NP / 4;
  const int CPN = CC * NP;
  for (size_t v = (size_t)blockIdx.x * 256 + threadIdx.x; v < NV;
       v += (size_t)gridDim.x * 256) {
    const size_t base = v * 4;
    const int bk = (int)(base / CPN);
    const int rem = (int)(base - (size_t)bk * CPN);
    int p0 = rem % NP;
    const float* fb = fs + (size_t)bk * NP;
    const int p1 = (p0 + 1 == NP) ? 0 : p0 + 1;
    const int p2 = (p1 + 1 == NP) ? 0 : p1 + 1;
    const int p3 = (p2 + 1 == NP) ? 0 : p2 + 1;
    float4 o = *(float4*)&outr[base];
    o.x *= fb[p0]; o.y *= fb[p1]; o.z *= fb[p2]; o.w *= fb[p3];
    *(float4*)&outr[base] = o;
  }
}

// ---------------------------------------------------------------------------
extern "C" void kernel_launch(void* const* d_in, const int* in_sizes, int n_in,
                              void* d_out, int out_size, void* d_ws, size_t ws_size,
                              hipStream_t stream)
{
  const float* x     = (const float*)d_in[0];
  const float* convw = (const float*)d_in[1];
  const float* cent  = (const float*)d_in[2];
  float* out = (float*)d_out;
  float* ws  = (float*)d_ws;

  float* xn    = ws;                                  // B*C*NPIX
  float* soft  = xn    + (size_t)BB * CC * NPIX;      // B*K*NPIX
  float* fs    = soft  + (size_t)BB * KK * NPIX;      // B*K*NP
  float* ghat  = fs    + (size_t)BB * KK * NP;        // B*K*C
  float* ssq   = ghat  + (size_t)BB * KK * CC;        // B*K*NP
  float* inv2g = ssq   + (size_t)BB * KK * NP;        // B

  float* outg = out + (size_t)BB * KK * CC * NP;

  k_norm_soft<<<dim3(HH, BB), 512, 0, stream>>>(x, convw, xn, soft);
  k_raw<<<dim3(8, 16, BB * 7), 320, 0, stream>>>(xn, soft, cent, out);
  k_global<<<dim3(KK, BB), 256, 0, stream>>>(xn, soft, cent, ghat);
  k_g2a<<<dim3(BB), 256, 0, stream>>>(ghat, inv2g);
  k_g2b<<<dim3((KK * CC + 255) / 256, BB), 256, 0, stream>>>(ghat, inv2g, outg);
  k_ssq<<<dim3(8, BB * KK), 256, 0, stream>>>(out, ssq);
  k_nf_b<<<dim3(HP, BB), 256, 0, stream>>>(ssq, fs);
  k_scale<<<dim3(2048), 256, 0, stream>>>(out, fs);
}

// Round 11
// 415.794 us; speedup vs baseline: 2.3139x; 2.3139x over previous
//
#include <hip/hip_runtime.h>
#include <math.h>

#define BB 2
#define CC 512
#define HH 30
#define WW 40
#define KK 64
#define NPIX (HH*WW)
#define HP 27
#define WP 37
#define NP (HP*WP)
#define LEPS 1e-12f

#define PADW 168      // xn ring row stride in floats (4*40 + 8 pad)
#define SROW 680      // soft slab floats per k (17 rows * 40)
#define NCG 8         // c-groups (64 c each)

// ---------------------------------------------------------------------------
// Kernel 1: per-(b,h) row: channel L2-norm, xn store, logits (K=64) + softmax.
// (unchanged from R4 — proven)
// ---------------------------------------------------------------------------
__global__ __launch_bounds__(512) void k_norm_soft(
    const float* __restrict__ x, const float* __restrict__ convw,
    float* __restrict__ xn, float* __restrict__ soft)
{
  const int h = blockIdx.x, b = blockIdx.y;
  const int t = threadIdx.x;
  __shared__ float xc[64][41];
  __shared__ float cw[64][65];
  __shared__ float Lb[KK][WW + 1];
  __shared__ float psum[12][WW];
  __shared__ float invn[WW];
  __shared__ float mx[WW], Zs[WW];

  const size_t xbase = (size_t)b * CC * NPIX + (size_t)h * WW;

  if (t < 480) {
    const int w = t % 40, part = t / 40;
    float s = 0.f;
    for (int c = part; c < CC; c += 12) {
      const float v = x[xbase + (size_t)c * NPIX + w];
      s = fmaf(v, v, s);
    }
    psum[part][w] = s;
  }
  __syncthreads();
  if (t < 40) {
    float s = 0.f;
    #pragma unroll
    for (int p = 0; p < 12; ++p) s += psum[p][t];
    invn[t] = 1.f / fmaxf(sqrtf(s), LEPS);
  }
  __syncthreads();

  const int k = t & 63, wp = t >> 6;
  float acc[5] = {0.f, 0.f, 0.f, 0.f, 0.f};
  for (int cb = 0; cb < CC; cb += 64) {
    #pragma unroll
    for (int n = 0; n < 5; ++n) {
      const int idx = t + 512 * n;
      const int c = idx / 40, w = idx % 40;
      const float v = x[xbase + (size_t)(cb + c) * NPIX + w] * invn[w];
      xc[c][w] = v;
      xn[xbase + (size_t)(cb + c) * NPIX + w] = v;
    }
    #pragma unroll
    for (int n = 0; n < 8; ++n) {
      const int idx = t + 512 * n;
      const int kk2 = idx >> 6, c2 = idx & 63;
      cw[kk2][c2] = convw[(size_t)kk2 * CC + cb + c2];
    }
    __syncthreads();
    #pragma unroll 1
    for (int c = 0; c < 64; ++c) {
      const float cv = cw[k][c];
      #pragma unroll
      for (int n = 0; n < 5; ++n)
        acc[n] = fmaf(cv, xc[c][wp + 8 * n], acc[n]);
    }
    __syncthreads();
  }
  #pragma unroll
  for (int n = 0; n < 5; ++n) Lb[k][wp + 8 * n] = acc[n];
  __syncthreads();
  if (t < 40) {
    float m = -1e30f;
    for (int kk2 = 0; kk2 < KK; ++kk2) m = fmaxf(m, Lb[kk2][t]);
    float Z = 0.f;
    for (int kk2 = 0; kk2 < KK; ++kk2) Z += expf(Lb[kk2][t] - m);
    mx[t] = m; Zs[t] = Z;
  }
  __syncthreads();
  const size_t sbase = (size_t)b * KK * NPIX + (size_t)h * WW;
  #pragma unroll
  for (int n = 0; n < 5; ++n) {
    const int idx = t + 512 * n;
    const int kk2 = idx / 40, w = idx % 40;
    soft[sbase + (size_t)kk2 * NPIX + w] = expf(Lb[kk2][w] - mx[w]) / Zs[w];
  }
}

// ---------------------------------------------------------------------------
// Kernel G: per-(b,k) global VLAD row, first L2 norm over c. (unchanged)
// ---------------------------------------------------------------------------
__global__ __launch_bounds__(256) void k_global(
    const float* __restrict__ xn, const float* __restrict__ soft,
    const float* __restrict__ cent, float* __restrict__ ghat)
{
  const int k = blockIdx.x, b = blockIdx.y, t = threadIdx.x;
  __shared__ float sb[NPIX];
  __shared__ float red[256];
  const float* srow = soft + ((size_t)b * KK + k) * NPIX;
  for (int i2 = t; i2 < NPIX; i2 += 256) sb[i2] = srow[i2];
  __syncthreads();
  float p = 0.f;
  for (int i2 = t; i2 < NPIX; i2 += 256) p += sb[i2];
  red[t] = p;
  __syncthreads();
  for (int s = 128; s > 0; s >>= 1) { if (t < s) red[t] += red[t + s]; __syncthreads(); }
  const float Sg = red[0];
  __syncthreads();

  const int c0 = t, c1 = t + 256;
  const float* x0 = xn + ((size_t)b * CC + c0) * NPIX;
  const float* x1 = xn + ((size_t)b * CC + c1) * NPIX;
  float a0 = 0.f, a1 = 0.f;
  for (int p4 = 0; p4 < NPIX; p4 += 4) {
    const float4 s4 = *(const float4*)&sb[p4];
    const float4 v0 = *(const float4*)(x0 + p4);
    const float4 v1 = *(const float4*)(x1 + p4);
    a0 = fmaf(s4.x, v0.x, a0); a0 = fmaf(s4.y, v0.y, a0);
    a0 = fmaf(s4.z, v0.z, a0); a0 = fmaf(s4.w, v0.w, a0);
    a1 = fmaf(s4.x, v1.x, a1); a1 = fmaf(s4.y, v1.y, a1);
    a1 = fmaf(s4.z, v1.z, a1); a1 = fmaf(s4.w, v1.w, a1);
  }
  const float g0 = a0 - cent[(size_t)k * CC + c0] * Sg;
  const float g1 = a1 - cent[(size_t)k * CC + c1] * Sg;
  red[t] = g0 * g0 + g1 * g1;
  __syncthreads();
  for (int s = 128; s > 0; s >>= 1) { if (t < s) red[t] += red[t + s]; __syncthreads(); }
  const float inv = 1.f / fmaxf(sqrtf(red[0]), LEPS);
  float* gr = ghat + ((size_t)b * KK + k) * CC;
  gr[c0] = g0 * inv; gr[c1] = g1 * inv;
}

// Global second norm: (a) per-b sum of squares -> inv scale, (b) wide scale.
__global__ __launch_bounds__(256) void k_g2a(
    const float* __restrict__ ghat, float* __restrict__ inv2g)
{
  const int b = blockIdx.x, t = threadIdx.x;
  __shared__ float red[256];
  const float* gb = ghat + (size_t)b * KK * CC;
  float p = 0.f;
  for (int i2 = t; i2 < KK * CC; i2 += 256) { const float v = gb[i2]; p = fmaf(v, v, p); }
  red[t] = p;
  __syncthreads();
  for (int s = 128; s > 0; s >>= 1) { if (t < s) red[t] += red[t + s]; __syncthreads(); }
  if (t == 0) inv2g[b] = 1.f / fmaxf(sqrtf(red[0]), LEPS);
}

__global__ __launch_bounds__(256) void k_g2b(
    const float* __restrict__ ghat, const float* __restrict__ inv2g,
    float* __restrict__ outg)
{
  const int b = blockIdx.y;
  const int u = blockIdx.x * 256 + threadIdx.x;
  if (u < KK * CC)
    outg[(size_t)b * KK * CC + u] = ghat[(size_t)b * KK * CC + u] * inv2g[b];
}

// ---------------------------------------------------------------------------
// Kernel RAWSSQ: R4's proven v5 k_local2 with the two phases MERGED into one
// pass. Per output row: compute raw (8c x 4k tile), store it unscaled
// (phase-1's lane-consecutive store map, no fs), and accumulate sum_c raw^2
// into the red buffer (phase-0's epilogue) -> sp partials per c-group.
// Ring/barrier discipline identical to R4 (2 barriers/iter, reg prefetch).
// ---------------------------------------------------------------------------
__global__ __launch_bounds__(320, 2) void k_rawssq(
    const float* __restrict__ xn, const float* __restrict__ soft,
    const float* __restrict__ cent, float* __restrict__ sp,
    float* __restrict__ out)
{
  const int cg = blockIdx.x;             // 0..7 (64 c)
  const int k0 = blockIdx.y * 4;         // k group
  const int bz = blockIdx.z;             // b*2 + iz
  const int b = bz >> 1, iz = bz & 1;
  const int i0 = iz * 14;
  const int n_i = iz ? 13 : 14;
  const int c0 = cg * 64;
  const int t = threadIdx.x;
  const int c8 = t / 40, j = t % 40;     // 8 c-subgroups x 40 cols

  __shared__ float xn_l[64][PADW];                       // 43008 B
  __shared__ float soft_l[4][SROW];                      // 10880 B
  __shared__ float cent_l[4][64];                        //  1024 B
  __shared__ float red[8 * 4 * 40];                      //  5120 B

  // stage soft slab
  {
    const int len = (NPIX - i0 * 40) < SROW ? (NPIX - i0 * 40) : SROW;
    const int nf4 = len >> 2;
    for (int u = t; u < 4 * nf4; u += 320) {
      const int kk = u / nf4, q = u - kk * nf4;
      *(float4*)&soft_l[kk][q * 4] =
        *(const float4*)&soft[((size_t)(b * KK + k0 + kk)) * NPIX + i0 * 40 + q * 4];
    }
  }
  if (t < 256) cent_l[t >> 6][t & 63] = cent[(size_t)(k0 + (t >> 6)) * CC + c0 + (t & 63)];

  const int sc = t / 10, sq = t % 10;
  // prologue: stage xn rows i0..i0+3 into ring
  #pragma unroll
  for (int rr = 0; rr < 4; ++rr) {
    const int row = i0 + rr;
    const int slot = (row & 3) * 40 + sq * 4;
    *(float4*)&xn_l[sc][slot] =
      *(const float4*)&xn[((size_t)(b * CC + c0 + sc)) * NPIX + (size_t)row * 40 + sq * 4];
    *(float4*)&xn_l[sc + 32][slot] =
      *(const float4*)&xn[((size_t)(b * CC + c0 + sc + 32)) * NPIX + (size_t)row * 40 + sq * 4];
  }
  __syncthreads();

  for (int ii = 0; ii < n_i; ++ii) {
    const int i = i0 + ii;

    // ---- prefetch row i+4 into registers (written to ring after barrier1)
    const int nrow = (i + 4 < HH) ? (i + 4) : (HH - 1);
    const float4 st0 = *(const float4*)&xn[((size_t)(b * CC + c0 + sc)) * NPIX
                                           + (size_t)nrow * 40 + sq * 4];
    const float4 st1 = *(const float4*)&xn[((size_t)(b * CC + c0 + sc + 32)) * NPIX
                                           + (size_t)nrow * 40 + sq * 4];

    // ---- compute (reads ring rows i..i+3, all staged) ----
    float sloc[4] = {0.f, 0.f, 0.f, 0.f};
    if (j < WP) {
      float acc[8][4];
      float Ssum[4] = {0.f, 0.f, 0.f, 0.f};
      #pragma unroll
      for (int cc = 0; cc < 8; ++cc)
        #pragma unroll
        for (int kk = 0; kk < 4; ++kk) acc[cc][kk] = 0.f;
      #pragma unroll
      for (int r = 0; r < 4; ++r) {
        const int xo = ((i + r) & 3) * 40 + j;
        const int so = (ii + r) * 40 + j;
        float sv[4][4];
        #pragma unroll
        for (int kk = 0; kk < 4; ++kk) {
          #pragma unroll
          for (int dx = 0; dx < 4; ++dx) sv[kk][dx] = soft_l[kk][so + dx];
          Ssum[kk] += (sv[kk][0] + sv[kk][1]) + (sv[kk][2] + sv[kk][3]);
        }
        #pragma unroll
        for (int cc = 0; cc < 8; ++cc) {
          const float x0 = xn_l[c8 * 8 + cc][xo + 0];
          const float x1 = xn_l[c8 * 8 + cc][xo + 1];
          const float x2 = xn_l[c8 * 8 + cc][xo + 2];
          const float x3 = xn_l[c8 * 8 + cc][xo + 3];
          #pragma unroll
          for (int kk = 0; kk < 4; ++kk) {
            float a = acc[cc][kk];
            a = fmaf(x0, sv[kk][0], a);
            a = fmaf(x1, sv[kk][1], a);
            a = fmaf(x2, sv[kk][2], a);
            a = fmaf(x3, sv[kk][3], a);
            acc[cc][kk] = a;
          }
        }
      }
      #pragma unroll
      for (int kk = 0; kk < 4; ++kk) {
        const float Sv = Ssum[kk];
        #pragma unroll
        for (int cc = 0; cc < 8; ++cc) {
          const float raw = fmaf(-cent_l[kk][c8 * 8 + cc], Sv, acc[cc][kk]);
          sloc[kk] = fmaf(raw, raw, sloc[kk]);
          out[((size_t)((b * KK + k0 + kk) * CC + c0 + c8 * 8 + cc)) * NP
              + (size_t)i * WP + j] = raw;
        }
      }
    }
    #pragma unroll
    for (int kk = 0; kk < 4; ++kk) red[(c8 * 4 + kk) * 40 + j] = sloc[kk];
    __syncthreads();   // barrier 1: ring slot i&3 free; red complete

    // ---- write prefetched row into slot (i+4)&3 (== i&3) ----
    {
      const int slot = ((i + 4) & 3) * 40 + sq * 4;
      *(float4*)&xn_l[sc][slot] = st0;
      *(float4*)&xn_l[sc + 32][slot] = st1;
    }
    if (t < 160) {
      const int kk = t / 40, jj = t % 40;
      if (jj < WP) {
        float s = 0.f;
        #pragma unroll
        for (int g = 0; g < 8; ++g) s += red[(g * 4 + kk) * 40 + jj];
        sp[(((size_t)(b * KK + k0 + kk)) * NCG + cg) * NP + (size_t)i * WP + jj] = s;
      }
    }
    __syncthreads();   // barrier 2: ring write + red reuse visible/safe
  }
}

// ---------------------------------------------------------------------------
// Kernel NF: per (b, 4 pixels): sum the 8 c-group partials, build the exact
// per-(b,k,p) scale with a 64-way LDS reduce for the cross-k second norm.
// ---------------------------------------------------------------------------
__global__ __launch_bounds__(256) void k_nf(
    const float* __restrict__ sp, float* __restrict__ fs)
{
  const int b = blockIdx.y, t = threadIdx.x;
  const int k = t >> 2, dp = t & 3;
  const int p = blockIdx.x * 4 + dp;
  __shared__ float red[64][4];
  __shared__ float inv2s[4];
  const bool ok = p < NP;
  float sr = 0.f;
  if (ok) {
    #pragma unroll
    for (int g = 0; g < NCG; ++g)
      sr += sp[(((size_t)(b * KK + k)) * NCG + g) * NP + p];
  }
  const float iv = 1.f / fmaxf(sqrtf(sr) * 0.0625f, LEPS);
  red[k][dp] = sr * (1.f / 256.f) * iv * iv;
  __syncthreads();
  if (t < 4) {
    float s = 0.f;
    #pragma unroll
    for (int kk = 0; kk < 64; ++kk) s += red[kk][t];
    inv2s[t] = 1.f / fmaxf(sqrtf(s), LEPS);
  }
  __syncthreads();
  if (ok)
    fs[((size_t)(b * KK + k)) * NP + p] = 0.0625f * iv * inv2s[dp];
}

// ---------------------------------------------------------------------------
// Kernel SCALE: in-place out[u] *= fs[bk][p]; aligned float4 RMW (proven).
// ---------------------------------------------------------------------------
__global__ __launch_bounds__(256) void k_scale(
    float* __restrict__ outr, const float* __restrict__ fs)
{
  const size_t NV = (size_t)BB * KK * CC * NP / 4;
  const int CPN = CC * NP;
  for (size_t v = (size_t)blockIdx.x * 256 + threadIdx.x; v < NV;
       v += (size_t)gridDim.x * 256) {
    const size_t base = v * 4;
    const int bk = (int)(base / CPN);
    const int rem = (int)(base - (size_t)bk * CPN);
    int p0 = rem % NP;
    const float* fb = fs + (size_t)bk * NP;
    const int p1 = (p0 + 1 == NP) ? 0 : p0 + 1;
    const int p2 = (p1 + 1 == NP) ? 0 : p1 + 1;
    const int p3 = (p2 + 1 == NP) ? 0 : p2 + 1;
    float4 o = *(float4*)&outr[base];
    o.x *= fb[p0]; o.y *= fb[p1]; o.z *= fb[p2]; o.w *= fb[p3];
    *(float4*)&outr[base] = o;
  }
}

// ---------------------------------------------------------------------------
extern "C" void kernel_launch(void* const* d_in, const int* in_sizes, int n_in,
                              void* d_out, int out_size, void* d_ws, size_t ws_size,
                              hipStream_t stream)
{
  const float* x     = (const float*)d_in[0];
  const float* convw = (const float*)d_in[1];
  const float* cent  = (const float*)d_in[2];
  float* out = (float*)d_out;
  float* ws  = (float*)d_ws;

  float* xn    = ws;                                  // B*C*NPIX
  float* soft  = xn    + (size_t)BB * CC * NPIX;      // B*K*NPIX
  float* fs    = soft  + (size_t)BB * KK * NPIX;      // B*K*NP
  float* ghat  = fs    + (size_t)BB * KK * NP;        // B*K*C
  float* sp    = ghat  + (size_t)BB * KK * CC;        // B*K*NCG*NP
  float* inv2g = sp    + (size_t)BB * KK * NCG * NP;  // B

  float* outg = out + (size_t)BB * KK * CC * NP;

  k_norm_soft<<<dim3(HH, BB), 512, 0, stream>>>(x, convw, xn, soft);
  k_rawssq<<<dim3(NCG, KK / 4, BB * 2), 320, 0, stream>>>(xn, soft, cent, sp, out);
  k_global<<<dim3(KK, BB), 256, 0, stream>>>(xn, soft, cent, ghat);
  k_g2a<<<dim3(BB), 256, 0, stream>>>(ghat, inv2g);
  k_g2b<<<dim3((KK * CC + 255) / 256, BB), 256, 0, stream>>>(ghat, inv2g, outg);
  k_nf<<<dim3((NP + 3) / 4, BB), 256, 0, stream>>>(sp, fs);
  k_scale<<<dim3(2048), 256, 0, stream>>>(out, fs);
}